// Round 1
// baseline (74.494 us; speedup 1.0000x reference)
//
#include <hip/hip_runtime.h>

constexpr int TAPS    = 50;   // M+1
constexpr int P       = 80;   // frame period
constexpr int BLOCK   = 256;
constexpr int R       = 4;    // outputs per thread (was 8)
constexpr int WFR     = 5;    // coeff frame slots per wave: 256 outputs span
                              // n_first..n_first+3, +1 interp partner
constexpr int FSTRIDE = 52;   // padded LDS frame stride (floats); 52*4B keeps
                              // per-frame ds_read_b128 bank-quads disjoint
constexpr int WAVES   = BLOCK / 64;
constexpr int XWIN    = 56;   // x window per thread: 52 back + R, 16B-aligned

// No __syncthreads: each wave stages its own coefficient frames into a
// wave-private LDS region (intra-wave ds ordering via compiler waitcnt).
__global__ __launch_bounds__(BLOCK) void azdf_kernel(
    const float* __restrict__ x, const float* __restrict__ b,
    float* __restrict__ y, int T, int N) {
  __shared__ float bs[WAVES * WFR * FSTRIDE];   // 4*5*52*4 = 4160 B

  const int batch = blockIdx.y;
  const int tid   = threadIdx.x;
  const int wave  = __builtin_amdgcn_readfirstlane(tid >> 6);
  const int lane  = tid & 63;
  const float* xb = x + (size_t)batch * T;
  const float* bb = b + (size_t)batch * N * TAPS;

  // first output t of this wave; 256 consecutive outputs per wave
  const int w0      = (blockIdx.x * BLOCK + wave * 64) * R;
  const int n_first = w0 / P;
  float* wbs = &bs[wave * WFR * FSTRIDE];

  const int t_base = w0 + lane * R;
  const bool active = (t_base < T);   // t_base%4==0 so full R outputs valid

  // ---- issue x-window loads FIRST so their latency overlaps staging ----
  // x[t_base-52 .. t_base+3] -> 56 regs; base 16B-aligned (t_base % 4 == 0)
  float xr[XWIN];
  if (active) {
    if (t_base >= 52) {
      const float* xp = xb + t_base - 52;
#pragma unroll
      for (int j = 0; j < XWIN / 4; ++j) {
        float4 v = *(const float4*)(xp + 4 * j);
        xr[4*j+0] = v.x; xr[4*j+1] = v.y; xr[4*j+2] = v.z; xr[4*j+3] = v.w;
      }
    } else {  // left edge: first 13 threads of each batch only
#pragma unroll
      for (int i = 0; i < XWIN; ++i) {
        int xi = t_base - 52 + i;
        xr[i] = (xi >= 0) ? xb[xi] : 0.0f;
      }
    }
  }

  // ---- wave-cooperative staging of frames n_first..n_first+4 (clamped) ----
  // b rows are 50 floats, 8B-aligned -> float2 vector staging, no int div.
  if (lane < TAPS / 2) {
#pragma unroll
    for (int f = 0; f < WFR; ++f) {
      int n = n_first + f;
      if (n > N - 1) n = N - 1;
      *(float2*)&wbs[f * FSTRIDE + 2 * lane] =
          *(const float2*)&bb[(size_t)n * TAPS + 2 * lane];
    }
  }

  if (!active) return;   // after staging: whole wave contributed

  const int n = t_base / P;                 // same frame for all R outputs
  const float* c0 = &wbs[(n - n_first) * FSTRIDE];
  const float* c1 = c0 + FSTRIDE;           // clamp applied at staging

  float s0[R], s1[R];
#pragma unroll
  for (int r = 0; r < R; ++r) { s0[r] = 0.0f; s1[r] = 0.0f; }

  // x[t_base + r - k] == xr[52 + r - k]
#pragma unroll
  for (int kc = 0; kc < 48; kc += 4) {
    float4 a0 = *(const float4*)&c0[kc];
    float4 a1 = *(const float4*)&c1[kc];
    const float av0[4] = {a0.x, a0.y, a0.z, a0.w};
    const float av1[4] = {a1.x, a1.y, a1.z, a1.w};
#pragma unroll
    for (int kk = 0; kk < 4; ++kk) {
      const int k = kc + kk;
#pragma unroll
      for (int r = 0; r < R; ++r) {
        float xv = xr[52 + r - k];
        s0[r] = fmaf(xv, av0[kk], s0[r]);
        s1[r] = fmaf(xv, av1[kk], s1[r]);
      }
    }
  }
  {  // tail k = 48, 49
    float2 a0 = *(const float2*)&c0[48];
    float2 a1 = *(const float2*)&c1[48];
#pragma unroll
    for (int r = 0; r < R; ++r) {
      float xv = xr[52 + r - 48];
      s0[r] = fmaf(xv, a0.x, s0[r]);
      s1[r] = fmaf(xv, a1.x, s1[r]);
    }
#pragma unroll
    for (int r = 0; r < R; ++r) {
      float xv = xr[52 + r - 49];
      s0[r] = fmaf(xv, a0.y, s0[r]);
      s1[r] = fmaf(xv, a1.y, s1[r]);
    }
  }

  const int phase = t_base - n * P;
  float out[R];
#pragma unroll
  for (int r = 0; r < R; ++r) {
    float w = (float)(phase + r) * (1.0f / (float)P);
    out[r] = (1.0f - w) * s0[r] + w * s1[r];
  }

  float* yp = y + (size_t)batch * T + t_base;   // 16B-aligned (t_base % 4 == 0)
  *(float4*)yp = make_float4(out[0], out[1], out[2], out[3]);
}

extern "C" void kernel_launch(void* const* d_in, const int* in_sizes, int n_in,
                              void* d_out, int out_size, void* d_ws, size_t ws_size,
                              hipStream_t stream) {
  const float* x = (const float*)d_in[0];
  const float* b = (const float*)d_in[1];
  float* y = (float*)d_out;

  const int B = 8;                         // fixed by setup_inputs
  const int N = in_sizes[1] / (B * TAPS);  // 3000
  const int T = N * P;                     // 240000

  const int threads_per_batch = T / R;     // 60000
  dim3 grid((threads_per_batch + BLOCK - 1) / BLOCK, B);
  azdf_kernel<<<grid, BLOCK, 0, stream>>>(x, b, y, T, N);
}

// Round 2
// 69.508 us; speedup vs baseline: 1.0717x; 1.0717x over previous
//
#include <hip/hip_runtime.h>

constexpr int TAPS    = 50;   // M+1
constexpr int P       = 80;   // frame period
constexpr int BLOCK   = 256;
constexpr int R       = 8;    // outputs per thread (revert to proven-better)
constexpr int WFR     = 9;    // coeff frame slots per wave (span 8 + interp partner)
constexpr int FSTRIDE = 52;   // coeff LDS frame stride: 208B => frames land on
                              // distinct bank-quads, per-lane frame reads conflict-free
constexpr int WAVES   = BLOCK / 64;
constexpr int WOUT    = 64 * R;           // 512 outputs per wave
constexpr int XWF     = WOUT + 52;        // 564 floats of x per wave window
constexpr int XWC     = XWF / 4;          // 141 16B chunks
constexpr int XBUF    = 576;              // 144 chunks; headroom for XOR swizzle
constexpr int CBUF    = WFR * FSTRIDE;    // 468
constexpr int WLDS    = XBUF + CBUF;      // 1044 floats per wave (4176 B)

// Wave-private LDS staging of BOTH x-window and coeff frames; no __syncthreads.
// x chunks are XOR-swizzled (c ^= (c>>3)&7) so that:
//  - staging writes (contiguous chunks per round) are conflict-free
//  - per-thread window reads (chunk = 2*lane + j, stride-2) spread across all
//    8 bank-quads per 8 lanes -> conflict-free b128 reads at BW floor.
__global__ __launch_bounds__(BLOCK) void azdf_kernel(
    const float* __restrict__ x, const float* __restrict__ b,
    float* __restrict__ y, int T, int N) {
  __shared__ __align__(16) float bs[WAVES * WLDS];   // 16.7 KB

  const int batch = blockIdx.y;
  const int tid   = threadIdx.x;
  const int wave  = tid >> 6;
  const int lane  = tid & 63;
  const float* xb = x + (size_t)batch * T;
  const float* bb = b + (size_t)batch * N * TAPS;

  const int w0 = (blockIdx.x * BLOCK + wave * 64) * R;  // first output of wave
  if (w0 >= T) return;                                   // wave-uniform exit

  float* xw  = &bs[wave * WLDS];   // x window: floats [w0-52 .. w0+511]
  float* wcs = xw + XBUF;          // coeff frames

  // ---- stage x window: 564 floats, coalesced, swizzled ----
  const bool edge = (w0 == 0) || (w0 + WOUT > T);
  if (!edge) {
    const float* xp = xb + (w0 - 52);   // w0 % 512 == 0 -> 16B aligned
#pragma unroll
    for (int rd = 0; rd < 3; ++rd) {
      int c = lane + rd * 64;
      if (c < XWC) {
        float4 v = *(const float4*)(xp + 4 * c);
        int cs = c ^ ((c >> 3) & 7);
        *(float4*)&xw[4 * cs] = v;
      }
    }
  } else {  // first / last wave of a batch: per-element bounds check
    for (int i = lane; i < XWF; i += 64) {
      int xi = w0 - 52 + i;
      float v = (xi >= 0 && xi < T) ? xb[xi] : 0.0f;
      int c  = i >> 2;
      int cs = c ^ ((c >> 3) & 7);
      xw[4 * cs + (i & 3)] = v;
    }
  }

  // ---- stage coeff frames n_first..n_first+8 (clamped), float2 rows ----
  const int n_first = w0 / P;
  if (lane < TAPS / 2) {
#pragma unroll
    for (int f = 0; f < WFR; ++f) {
      int n = n_first + f;
      if (n > N - 1) n = N - 1;
      *(float2*)&wcs[f * FSTRIDE + 2 * lane] =
          *(const float2*)&bb[(size_t)n * TAPS + 2 * lane];
    }
  }

  const int t_base = w0 + lane * R;
  if (t_base >= T) return;   // after staging: whole wave contributed

  // ---- read per-thread x window from LDS (swizzled b128 reads) ----
  // xr[i] = x[t_base - 52 + i]; window float index within wave buf = 8*lane + i
  float xr[60];
#pragma unroll
  for (int j = 0; j < 15; ++j) {
    int c  = 2 * lane + j;
    int cs = c ^ ((c >> 3) & 7);
    float4 v = *(const float4*)&xw[4 * cs];
    xr[4*j+0] = v.x; xr[4*j+1] = v.y; xr[4*j+2] = v.z; xr[4*j+3] = v.w;
  }

  const int n = t_base / P;                 // same frame for all R outputs
  const float* c0 = &wcs[(n - n_first) * FSTRIDE];
  const float* c1 = c0 + FSTRIDE;           // clamp applied at staging

  float s0[R], s1[R];
#pragma unroll
  for (int r = 0; r < R; ++r) { s0[r] = 0.0f; s1[r] = 0.0f; }

  // x[t_base + r - k] == xr[52 + r - k]
#pragma unroll
  for (int kc = 0; kc < 48; kc += 4) {
    float4 a0 = *(const float4*)&c0[kc];
    float4 a1 = *(const float4*)&c1[kc];
    const float av0[4] = {a0.x, a0.y, a0.z, a0.w};
    const float av1[4] = {a1.x, a1.y, a1.z, a1.w};
#pragma unroll
    for (int kk = 0; kk < 4; ++kk) {
      const int k = kc + kk;
#pragma unroll
      for (int r = 0; r < R; ++r) {
        float xv = xr[52 + r - k];
        s0[r] = fmaf(xv, av0[kk], s0[r]);
        s1[r] = fmaf(xv, av1[kk], s1[r]);
      }
    }
  }
  {  // tail k = 48, 49
    float2 a0 = *(const float2*)&c0[48];
    float2 a1 = *(const float2*)&c1[48];
#pragma unroll
    for (int r = 0; r < R; ++r) {
      float xv = xr[52 + r - 48];
      s0[r] = fmaf(xv, a0.x, s0[r]);
      s1[r] = fmaf(xv, a1.x, s1[r]);
    }
#pragma unroll
    for (int r = 0; r < R; ++r) {
      float xv = xr[52 + r - 49];
      s0[r] = fmaf(xv, a0.y, s0[r]);
      s1[r] = fmaf(xv, a1.y, s1[r]);
    }
  }

  const int phase = t_base - n * P;
  float out[R];
#pragma unroll
  for (int r = 0; r < R; ++r) {
    float w = (float)(phase + r) * (1.0f / (float)P);
    out[r] = (1.0f - w) * s0[r] + w * s1[r];
  }

  float* yp = y + (size_t)batch * T + t_base;   // 32B-aligned (t_base % 8 == 0)
  *(float4*)(yp + 0) = make_float4(out[0], out[1], out[2], out[3]);
  *(float4*)(yp + 4) = make_float4(out[4], out[5], out[6], out[7]);
}

extern "C" void kernel_launch(void* const* d_in, const int* in_sizes, int n_in,
                              void* d_out, int out_size, void* d_ws, size_t ws_size,
                              hipStream_t stream) {
  const float* x = (const float*)d_in[0];
  const float* b = (const float*)d_in[1];
  float* y = (float*)d_out;

  const int B = 8;                         // fixed by setup_inputs
  const int N = in_sizes[1] / (B * TAPS);  // 3000
  const int T = N * P;                     // 240000

  const int threads_per_batch = T / R;     // 30000
  dim3 grid((threads_per_batch + BLOCK - 1) / BLOCK, B);
  azdf_kernel<<<grid, BLOCK, 0, stream>>>(x, b, y, T, N);
}

// Round 3
// 68.390 us; speedup vs baseline: 1.0893x; 1.0164x over previous
//
#include <hip/hip_runtime.h>

typedef float v2f __attribute__((ext_vector_type(2)));
typedef float v4f __attribute__((ext_vector_type(4)));

constexpr int TAPS    = 50;   // M+1
constexpr int P       = 80;   // frame period
constexpr int BLOCK   = 256;
constexpr int R       = 8;    // outputs per thread
constexpr int NPB     = 8;    // frame-PAIR buffers per wave (l = 0..7)
constexpr int PSTRIDE = 104;  // floats per pair-buffer (2*50 interleaved + pad)
constexpr int WAVES   = BLOCK / 64;
constexpr int WOUT    = 64 * R;           // 512 outputs per wave
constexpr int XWF     = WOUT + 52;        // 564 floats of x per wave window
constexpr int XWC     = XWF / 4;          // 141 16B chunks
constexpr int XBUF    = 576;              // chunk slots incl. XOR-swizzle headroom
constexpr int CBUF    = NPB * PSTRIDE;    // 832
constexpr int WLDS    = XBUF + CBUF;      // 1408 floats (5632 B) per wave

// Wave-private LDS staging (no __syncthreads; intra-wave ds ordering via
// compiler waitcnt).
//  - x window XOR-swizzled for conflict-free b128 staging + reads (as r2).
//  - coeff frames staged INTERLEAVED per frame-pair l: position 2k,2k+1 =
//    (b[n_first+l][k], b[n_first+l+1][k]) so one ds_read_b128 delivers two
//    packed-v2f coefficient operands -> v_pk_fma_f32 inner loop
//    ({s0,s1} accumulated together; FMA instr count halves 800 -> 400/thread).
__global__ __launch_bounds__(BLOCK) void azdf_kernel(
    const float* __restrict__ x, const float* __restrict__ b,
    float* __restrict__ y, int T, int N) {
  __shared__ __align__(16) float bs[WAVES * WLDS];   // 22.5 KB

  const int batch = blockIdx.y;
  const int tid   = threadIdx.x;
  const int wave  = tid >> 6;
  const int lane  = tid & 63;
  const float* xb = x + (size_t)batch * T;
  const float* bb = b + (size_t)batch * N * TAPS;

  const int w0 = (blockIdx.x * BLOCK + wave * 64) * R;  // first output of wave
  if (w0 >= T) return;                                   // wave-uniform exit

  float* xw  = &bs[wave * WLDS];   // x window: floats [w0-52 .. w0+511]
  float* wcs = xw + XBUF;          // interleaved coeff pair-buffers

  // ---- stage x window: 564 floats, coalesced, swizzled ----
  const bool edge = (w0 == 0) || (w0 + WOUT > T);
  if (!edge) {
    const float* xp = xb + (w0 - 52);   // w0 % 512 == 0 -> 16B aligned
#pragma unroll
    for (int rd = 0; rd < 3; ++rd) {
      int c = lane + rd * 64;
      if (c < XWC) {
        float4 v = *(const float4*)(xp + 4 * c);
        int cs = c ^ ((c >> 3) & 7);
        *(float4*)&xw[4 * cs] = v;
      }
    }
  } else {  // first / last wave of a batch: per-element bounds check
    for (int i = lane; i < XWF; i += 64) {
      int xi = w0 - 52 + i;
      float v = (xi >= 0 && xi < T) ? xb[xi] : 0.0f;
      int c  = i >> 2;
      int cs = c ^ ((c >> 3) & 7);
      xw[4 * cs + (i & 3)] = v;
    }
  }

  // ---- stage interleaved coeff pair-buffers l = 0..7 ----
  // item = (l, j): l = pair-buffer, j = tap-pair (taps 2j, 2j+1), j < 25.
  const int n_first = w0 / P;
#pragma unroll
  for (int rd = 0; rd < 4; ++rd) {
    int item = lane + rd * 64;        // 256 items = 8 l x 32 j-slots
    int l = item >> 5, j = item & 31;
    if (j < 25) {
      int n0 = n_first + l;     if (n0 > N - 1) n0 = N - 1;
      int n1 = n_first + l + 1; if (n1 > N - 1) n1 = N - 1;
      v2f a = *(const v2f*)&bb[(size_t)n0 * TAPS + 2 * j];
      v2f c = *(const v2f*)&bb[(size_t)n1 * TAPS + 2 * j];
      v4f q = {a.x, c.x, a.y, c.y};   // (b0[2j], b1[2j], b0[2j+1], b1[2j+1])
      *(v4f*)&wcs[l * PSTRIDE + 4 * j] = q;
    }
  }

  const int t_base = w0 + lane * R;
  if (t_base >= T) return;   // after staging: whole wave contributed

  // ---- read per-thread x window from LDS (swizzled b128 reads) ----
  float xr[60];   // xr[i] = x[t_base - 52 + i]
#pragma unroll
  for (int j = 0; j < 15; ++j) {
    int c  = 2 * lane + j;
    int cs = c ^ ((c >> 3) & 7);
    float4 v = *(const float4*)&xw[4 * cs];
    xr[4*j+0] = v.x; xr[4*j+1] = v.y; xr[4*j+2] = v.z; xr[4*j+3] = v.w;
  }

  const int n = t_base / P;           // same frame for all R outputs
  const int l = n - n_first;          // 0..7
  const float* cb = &wcs[l * PSTRIDE];

  v2f acc[R];                         // acc[r] = {s0[r], s1[r]}
#pragma unroll
  for (int r = 0; r < R; ++r) acc[r] = (v2f)0.0f;

  // x[t_base + r - k] == xr[52 + r - k]; k = 2j, 2j+1
#pragma unroll
  for (int j = 0; j < 25; ++j) {
    v4f q = *(const v4f*)&cb[4 * j];
    v2f cA = q.xy;                    // (b0[2j],   b1[2j])
    v2f cB = q.zw;                    // (b0[2j+1], b1[2j+1])
#pragma unroll
    for (int r = 0; r < R; ++r)
      acc[r] = __builtin_elementwise_fma((v2f)xr[52 + r - 2*j], cA, acc[r]);
#pragma unroll
    for (int r = 0; r < R; ++r)
      acc[r] = __builtin_elementwise_fma((v2f)xr[51 + r - 2*j], cB, acc[r]);
  }

  const int phase = t_base - n * P;
  float out[R];
#pragma unroll
  for (int r = 0; r < R; ++r) {
    float w = (float)(phase + r) * (1.0f / (float)P);
    out[r] = (1.0f - w) * acc[r].x + w * acc[r].y;
  }

  float* yp = y + (size_t)batch * T + t_base;   // 32B-aligned (t_base % 8 == 0)
  *(float4*)(yp + 0) = make_float4(out[0], out[1], out[2], out[3]);
  *(float4*)(yp + 4) = make_float4(out[4], out[5], out[6], out[7]);
}

extern "C" void kernel_launch(void* const* d_in, const int* in_sizes, int n_in,
                              void* d_out, int out_size, void* d_ws, size_t ws_size,
                              hipStream_t stream) {
  const float* x = (const float*)d_in[0];
  const float* b = (const float*)d_in[1];
  float* y = (float*)d_out;

  const int B = 8;                         // fixed by setup_inputs
  const int N = in_sizes[1] / (B * TAPS);  // 3000
  const int T = N * P;                     // 240000

  const int threads_per_batch = T / R;     // 30000
  dim3 grid((threads_per_batch + BLOCK - 1) / BLOCK, B);
  azdf_kernel<<<grid, BLOCK, 0, stream>>>(x, b, y, T, N);
}